// Round 3
// baseline (442.336 us; speedup 1.0000x reference)
//
#include <hip/hip_runtime.h>
#include <math.h>
#include <stdint.h>

#define B_ 8
#define S_ 2048
#define E_ 1024
#define D_ 64
#define LDK 72   // LDS row stride in bf16 elems (64 + 8 pad)

typedef __attribute__((ext_vector_type(8))) short bf16x8;
typedef __attribute__((ext_vector_type(4))) float f32x4;

static __device__ __forceinline__ unsigned short f2bf(float f) {
    union { float f; unsigned u; } v; v.f = f;
    unsigned r = v.u + 0x7FFFu + ((v.u >> 16) & 1u);   // RNE
    return (unsigned short)(r >> 16);
}

// packed bf16 pair via HW cvt (RNE, matches f2bf for normal floats):
// D[15:0]=bf16(lo), D[31:16]=bf16(hi)
static __device__ __forceinline__ unsigned cvtpk(float lo, float hi) {
    unsigned r;
    asm("v_cvt_pk_bf16_f32 %0, %1, %2" : "=v"(r) : "v"(lo), "v"(hi));
    return r;
}

// ---------------------------------------------------------------------------
// K0: convert W (fp32 [3][64][1024]) -> bf16, same layout (L2-resident, 384 KB).
// ---------------------------------------------------------------------------
__global__ __launch_bounds__(256) void wconv_kernel(
    const float* __restrict__ Wq, const float* __restrict__ Wk,
    const float* __restrict__ Wv, unsigned short* __restrict__ Wb)
{
    const int which = blockIdx.x >> 6;                 // 64 blocks per matrix
    const float* W = (which == 0) ? Wq : (which == 1) ? Wk : Wv;
    const int i = ((blockIdx.x & 63) * 256 + threadIdx.x) * 4;
    float4 v = *(const float4*)(W + i);
    union { unsigned u32[2]; ushort4 s; } o;
    o.u32[0] = cvtpk(v.x, v.y);
    o.u32[1] = cvtpk(v.z, v.w);
    *(ushort4*)(Wb + (size_t)which * 65536 + i) = o.s;
}

// ---------------------------------------------------------------------------
// K1: projections, NO LDS / NO barriers. Each wave owns 16 output rows.
// A-frag: lane reads X fp32 from global (nontemporal, read-once), converts
// in-register with v_cvt_pk_bf16_f32 (was the VALU hotspot: 5-op bit-twiddle
// per element -> 1 op per 2 elements). B-frag: bf16 W from global (L2 hit).
// which==2 (V) emits transposed VT[b][d][s] for PV's B operand.
// ---------------------------------------------------------------------------
__global__ __launch_bounds__(256) void proj_kernel(
    const float* __restrict__ Xq, const float* __restrict__ Xk,
    const float* __restrict__ Xv, const unsigned short* __restrict__ Wb,
    unsigned short* __restrict__ Qb, unsigned short* __restrict__ Kb,
    unsigned short* __restrict__ VTb)
{
    const int which = blockIdx.y;
    const float* __restrict__ X = (which == 0) ? Xq : (which == 1) ? Xk : Xv;
    const unsigned short* __restrict__ W = Wb + (size_t)which * 65536;

    const int tid  = threadIdx.x;
    const int lane = tid & 63;
    const int wv   = tid >> 6;
    const int quad = lane >> 4;
    const int l15  = lane & 15;
    const int m    = blockIdx.x * 64 + wv * 16 + l15;   // A-frag row for this lane

    f32x4 acc[4];
    #pragma unroll
    for (int i = 0; i < 4; i++) { f32x4 z = {0.f, 0.f, 0.f, 0.f}; acc[i] = z; }

    const float* __restrict__ xrow = X + (size_t)m * E_;

    #pragma unroll 2
    for (int e0 = 0; e0 < E_; e0 += 64) {
        #pragma unroll
        for (int ks = 0; ks < 2; ks++) {
            const int k = e0 + ks * 32 + quad * 8;
            f32x4 a0 = __builtin_nontemporal_load((const f32x4*)(xrow + k));
            f32x4 a1 = __builtin_nontemporal_load((const f32x4*)(xrow + k + 4));
            union { unsigned u32[4]; bf16x8 v; } af;
            af.u32[0] = cvtpk(a0[0], a0[1]);
            af.u32[1] = cvtpk(a0[2], a0[3]);
            af.u32[2] = cvtpk(a1[0], a1[1]);
            af.u32[3] = cvtpk(a1[2], a1[3]);
            #pragma unroll
            for (int nt = 0; nt < 4; nt++) {
                bf16x8 bf = *(const bf16x8*)(W + (size_t)(16 * nt + l15) * E_ + k);
                acc[nt] = __builtin_amdgcn_mfma_f32_16x16x32_bf16(af.v, bf, acc[nt], 0, 0, 0);
            }
        }
    }

    // C/D layout (verified): row = quad*4 + reg (within wave's 16), col = 16*nt + l15
    if (which < 2) {
        unsigned short* O = (which == 0) ? Qb : Kb;
        #pragma unroll
        for (int nt = 0; nt < 4; nt++)
            #pragma unroll
            for (int reg = 0; reg < 4; reg++) {
                int mg = blockIdx.x * 64 + wv * 16 + quad * 4 + reg;
                int d  = 16 * nt + l15;
                O[(size_t)mg * D_ + d] = f2bf(acc[nt][reg]);
            }
    } else {
        #pragma unroll
        for (int nt = 0; nt < 4; nt++)
            #pragma unroll
            for (int reg = 0; reg < 4; reg++) {
                int mg = blockIdx.x * 64 + wv * 16 + quad * 4 + reg;
                int b  = mg >> 11, sl = mg & 2047;
                int d  = 16 * nt + l15;
                VTb[((size_t)b * D_ + d) * S_ + sl] = f2bf(acc[nt][reg]);
            }
    }
}

// ---------------------------------------------------------------------------
// K2: fused attention. Per block: 32 query rows of one batch. 8 waves =
// (msub 0..1) x (nsub 0..3) 16x16 tiles of the 32x64 (s x t / s x d) outputs.
//
// This revision removes ALL K/Q LDS staging: Kb is L2-resident per-XCD
// (256 KB/batch, batch->XCD affinity), so K B-frags are read straight from
// global with depth-1 register prefetch; Q A-frags are loop-invariant and
// live in 8 VGPRs. Pass A has ZERO barriers. Pass B runs ONE barrier/iter
// with double-buffered Ps (barrier at iter t orders reads(p)@t-1 before
// writes(p)@t+1). Mask is bit-packed once in the prologue; per-iter mask
// access is a single ds_read_u8 + shift.
// ---------------------------------------------------------------------------
__global__ __launch_bounds__(512) void attn_kernel(
    const unsigned short* __restrict__ Qb, const unsigned short* __restrict__ Kb,
    const unsigned short* __restrict__ VTb, const unsigned char* __restrict__ mask,
    float* __restrict__ Sc, float* __restrict__ Att)
{
    __shared__ unsigned short Ps[2][32 * LDK];
    __shared__ unsigned char  Mb[32 * 32 * 8];   // [it][sl][8B] bit-packed mask
    __shared__ float Sums[4 * 32];
    __shared__ float Inv[32];

    const int tid  = threadIdx.x;
    const int lane = tid & 63;
    const int wv   = tid >> 6;        // 0..7
    const int quad = lane >> 4, l15 = lane & 15;
    const int msub = wv >> 2, nsub = wv & 3;
    const int b  = blockIdx.x & 7;            // batch -> XCD affinity
    const int sB = (blockIdx.x >> 3) * 32;

    // ---- prologue: pack ALL mask bits (32 its x 32 rows x 64 cols) ----
    {
        const int ith = tid >> 8;              // 0..1 (it halves)
        const int r   = (tid & 255) >> 3;      // 0..31
        const int c8  = tid & 7;               // 0..7
        #pragma unroll 4
        for (int il = 0; il < 16; il++) {
            const int it = ith * 16 + il;
            unsigned long long u = __builtin_nontemporal_load(
                (const unsigned long long*)(mask +
                    ((size_t)(b * S_ + sB + r)) * S_ + it * 64 + c8 * 8));
            unsigned x = (unsigned)u, y = (unsigned)(u >> 32);
            unsigned n0 = (x | (x >> 7) | (x >> 14) | (x >> 21)) & 0xFu;
            unsigned n1 = (y | (y >> 7) | (y >> 14) | (y >> 21)) & 0xFu;
            Mb[(it * 32 + r) * 8 + c8] = (unsigned char)(n0 | (n1 << 4));
        }
    }

    // ---- hoist Q A-frags into registers (loop-invariant, both passes) ----
    const unsigned short* __restrict__ qrow =
        Qb + ((size_t)(b * S_ + sB + 16 * msub + l15)) * D_;
    const bf16x8 aq0 = *(const bf16x8*)(qrow + quad * 8);
    const bf16x8 aq1 = *(const bf16x8*)(qrow + 32 + quad * 8);

    const unsigned short* __restrict__ krow =
        Kb + ((size_t)(b * S_ + 16 * nsub + l15)) * D_;
    const unsigned short* __restrict__ vrow =
        VTb + ((size_t)(b * D_ + 16 * nsub + l15)) * S_;

    const int mbyte = (16 * nsub + l15) >> 3;  // byte within Mb[it][sl] word
    const int mbit  = l15 & 7;

    __syncthreads();   // Mb ready (the ONLY barrier before the pass-B loop)

    // ---------------- pass A: row sums of exp(logit), NO barriers ----------------
    float sum_[4] = {0.f, 0.f, 0.f, 0.f};
    bf16x8 kf0 = *(const bf16x8*)(krow + quad * 8);
    bf16x8 kf1 = *(const bf16x8*)(krow + 32 + quad * 8);
    #pragma unroll 2
    for (int it = 0; it < 32; it++) {
        bf16x8 nf0, nf1;
        if (it + 1 < 32) {   // depth-1 register prefetch of next K frags
            nf0 = *(const bf16x8*)(krow + (it + 1) * (64 * D_) + quad * 8);
            nf1 = *(const bf16x8*)(krow + (it + 1) * (64 * D_) + 32 + quad * 8);
        }
        f32x4 a = {0.f, 0.f, 0.f, 0.f};
        a = __builtin_amdgcn_mfma_f32_16x16x32_bf16(aq0, kf0, a, 0, 0, 0);
        a = __builtin_amdgcn_mfma_f32_16x16x32_bf16(aq1, kf1, a, 0, 0, 0);
        #pragma unroll
        for (int reg = 0; reg < 4; reg++) {
            int sl = 16 * msub + quad * 4 + reg;
            unsigned char mb = Mb[(it * 32 + sl) * 8 + mbyte];
            int bit = (mb >> mbit) & 1;
            float e = bit ? 0.f : __expf(a[reg] * 0.125f);
            sum_[reg] += e;
        }
        kf0 = nf0; kf1 = nf1;
    }
    // reduce over the 16 l15 lanes (t-subset cols within this nsub group)
    #pragma unroll
    for (int off = 1; off < 16; off <<= 1)
        #pragma unroll
        for (int reg = 0; reg < 4; reg++)
            sum_[reg] += __shfl_xor(sum_[reg], off);
    if (l15 == 0) {
        #pragma unroll
        for (int reg = 0; reg < 4; reg++)
            Sums[nsub * 32 + 16 * msub + quad * 4 + reg] = sum_[reg];
    }
    __syncthreads();
    if (tid < 32) {
        float s = Sums[tid] + Sums[32 + tid] + Sums[64 + tid] + Sums[96 + tid];
        Inv[tid] = 1.0f / s;
    }
    __syncthreads();   // Inv ready

    // ---------------- pass B: emit probs + PV, ONE barrier/iter ----------------
    f32x4 acc = {0.f, 0.f, 0.f, 0.f};
    kf0 = *(const bf16x8*)(krow + quad * 8);
    kf1 = *(const bf16x8*)(krow + 32 + quad * 8);
    for (int it = 0; it < 32; it++) {
        const int t0 = it * 64;
        // prefetch VT B-frags (consumed after the barrier) + next K frags
        bf16x8 vf0 = *(const bf16x8*)(vrow + t0 + quad * 8);
        bf16x8 vf1 = *(const bf16x8*)(vrow + t0 + 32 + quad * 8);
        bf16x8 nf0, nf1;
        if (it + 1 < 32) {
            nf0 = *(const bf16x8*)(krow + (it + 1) * (64 * D_) + quad * 8);
            nf1 = *(const bf16x8*)(krow + (it + 1) * (64 * D_) + 32 + quad * 8);
        }
        f32x4 a = {0.f, 0.f, 0.f, 0.f};
        a = __builtin_amdgcn_mfma_f32_16x16x32_bf16(aq0, kf0, a, 0, 0, 0);
        a = __builtin_amdgcn_mfma_f32_16x16x32_bf16(aq1, kf1, a, 0, 0, 0);
        #pragma unroll
        for (int reg = 0; reg < 4; reg++) {
            int sl = 16 * msub + quad * 4 + reg;
            unsigned char mb = Mb[(it * 32 + sl) * 8 + mbyte];
            int bit = (mb >> mbit) & 1;
            float p = bit ? 0.f : __expf(a[reg] * 0.125f) * Inv[sl];
            __builtin_nontemporal_store(p,
                &Sc[((size_t)(b * S_ + sB + sl)) * S_ + t0 + 16 * nsub + l15]);
            Ps[it & 1][sl * LDK + 16 * nsub + l15] = f2bf(p);
        }
        __syncthreads();   // Ps[it&1] ready; also orders next iter's writes
        #pragma unroll
        for (int ks = 0; ks < 2; ks++) {
            bf16x8 af = *(const bf16x8*)&Ps[it & 1][(16 * msub + l15) * LDK + ks * 32 + quad * 8];
            acc = __builtin_amdgcn_mfma_f32_16x16x32_bf16(af, (ks == 0) ? vf0 : vf1, acc, 0, 0, 0);
        }
        kf0 = nf0; kf1 = nf1;
    }
    #pragma unroll
    for (int reg = 0; reg < 4; reg++) {
        int sl = 16 * msub + quad * 4 + reg;
        __builtin_nontemporal_store(acc[reg],
            &Att[((size_t)(b * S_ + sB + sl)) * D_ + 16 * nsub + l15]);
    }
}

// ---------------------------------------------------------------------------
extern "C" void kernel_launch(void* const* d_in, const int* in_sizes, int n_in,
                              void* d_out, int out_size, void* d_ws, size_t ws_size,
                              hipStream_t stream)
{
    const float* q  = (const float*)d_in[0];
    const float* k  = (const float*)d_in[1];
    const float* v  = (const float*)d_in[2];
    const unsigned char* mask = (const unsigned char*)d_in[3];
    const float* wq = (const float*)d_in[4];
    const float* wk = (const float*)d_in[5];
    const float* wv = (const float*)d_in[6];

    float* out = (float*)d_out;
    float* Att = out;                                  // [B,S,D]
    float* Sc  = out + (size_t)B_ * S_ * D_;           // [B,S,S]

    // ws: Wb (384 KB) | Qb (2MB) | Kb (2MB) | VT (2MB)
    unsigned short* Wb = (unsigned short*)d_ws;
    unsigned short* Qb = Wb + (size_t)3 * 65536;
    unsigned short* Kb = Qb + (size_t)B_ * S_ * D_;
    unsigned short* VT = Kb + (size_t)B_ * S_ * D_;

    hipLaunchKernelGGL(wconv_kernel, dim3(192), dim3(256), 0, stream, wq, wk, wv, Wb);
    hipLaunchKernelGGL(proj_kernel, dim3(256, 3), dim3(256), 0, stream,
                       q, k, v, Wb, Qb, Kb, VT);
    hipLaunchKernelGGL(attn_kernel, dim3(512), dim3(512), 0, stream,
                       Qb, Kb, VT, mask, Sc, Att);
}